// Round 6
// baseline (1173.009 us; speedup 1.0000x reference)
//
#include <hip/hip_runtime.h>
#include <hip/hip_fp16.h>

#define TT   2048
#define BB   64
#define II   16
#define HH   8
#define HIDN 64
#define GG   256   // 4*HIDN
#define T4   (TT / 4)

typedef _Float16 h2 __attribute__((ext_vector_type(2)));
typedef _Float16 h4 __attribute__((ext_vector_type(4)));
typedef _Float16 h8 __attribute__((ext_vector_type(8)));

__device__ __forceinline__ float fdot2(h2 a, h2 b, float c) {
    return __builtin_amdgcn_fdot2(a, b, c, false);
}
__device__ __forceinline__ float fast_sigmoid(float z) {
    return __builtin_amdgcn_rcpf(1.0f + __expf(-z));
}
__device__ __forceinline__ float fast_tanh(float z) {
    return fmaf(2.0f, __builtin_amdgcn_rcpf(1.0f + __expf(-2.0f * z)), -1.0f);
}

// Opaque register pin: makes the value an asm output -> the compiler can no
// longer REMATERIALIZE it by re-loading from global inside the loop (the
// root cause of the ~990us floor: VGPR_Count=124 < ~200 regs of declared
// weight state => per-step L2 weight reloads, ~34GB of L2 traffic/launch
// which at ~34.5TB/s aggregate L2 BW is ~990us -- the measured duration).
__device__ __forceinline__ void pin_h2(h2& v) {
    int t = __builtin_bit_cast(int, v);
    asm volatile("" : "+v"(t));
    v = __builtin_bit_cast(h2, t);
}
__device__ __forceinline__ void pin_f(float& v) {
    asm volatile("" : "+v"(v));
}

// ---------------- x -> f16 conversion (one-time, trivial) ----------------
__global__ void cvt_x_kernel(const float* __restrict__ x, _Float16* __restrict__ xh, int n4) {
    int i = blockIdx.x * blockDim.x + threadIdx.x;
    if (i < n4) {
        float4 v = ((const float4*)x)[i];
        ((h2*)xh)[2 * i]     = h2{ (_Float16)v.x, (_Float16)v.y };
        ((h2*)xh)[2 * i + 1] = h2{ (_Float16)v.z, (_Float16)v.w };
    }
}

// ------------- main recurrent kernel: SGPR-broadcast h, zero LDS -----------
// One wave per chain (512 blocks x 64 threads). h broadcast via
// dpp-pack + v_readlane -> SGPR (fdot2's one scalar operand). No ds ops,
// no lgkmcnt in the loop.
// THIS ROUND: keep weights resident in VGPRs.
//  * amdgpu_waves_per_eu(1,1): tells the scheduler occupancy target is 1
//    wave/EU -> stop minimizing VGPRs at the cost of in-loop reloads.
//  * pin_h2/pin_f on every weight register after conversion: values become
//    asm outputs -> rematerialization-by-reload is semantically illegal;
//    ~220 VGPRs resident, well under the 512 budget (no spill expected).
__global__ __launch_bounds__(64, 1) __attribute__((amdgpu_waves_per_eu(1, 1)))
void lstm_rl(const _Float16* __restrict__ xh,
             const float* __restrict__ Wih,
             const float* __restrict__ Whh,
             const float* __restrict__ bih,
             const float* __restrict__ bhh,
             _Float16* __restrict__ stage_f16)   // [t4][chain][unit][4] h4
{
    const int lane = threadIdx.x;          // hidden unit index
    const int c    = blockIdx.x;           // chain id
    const int b    = c & (BB - 1);
    const int hd   = c >> 6;
    const bool odd = lane & 1;

    // ---- per-lane weights: the 4 gate rows of this unit, f16 in VGPRs ----
    h2 whh[4][HIDN / 2];
    h2 wih[4][II / 2];
    float bias[4];
#pragma unroll
    for (int g = 0; g < 4; ++g) {
        const int r = hd * GG + g * HIDN + lane;  // PyTorch gate-major row
        const float4* p = (const float4*)(Whh + (size_t)r * HIDN);
#pragma unroll
        for (int q = 0; q < HIDN / 4; ++q) {
            float4 v = p[q];
            whh[g][2 * q]     = h2{ (_Float16)v.x, (_Float16)v.y };
            whh[g][2 * q + 1] = h2{ (_Float16)v.z, (_Float16)v.w };
        }
        const float4* pi = (const float4*)(Wih + (size_t)r * II);
#pragma unroll
        for (int q = 0; q < II / 4; ++q) {
            float4 v = pi[q];
            wih[g][2 * q]     = h2{ (_Float16)v.x, (_Float16)v.y };
            wih[g][2 * q + 1] = h2{ (_Float16)v.z, (_Float16)v.w };
        }
        bias[g] = bih[r] + bhh[r];
    }

    // ---- pin all weight state into VGPRs (one-time, zero dynamic cost) ----
#pragma unroll
    for (int g = 0; g < 4; ++g) {
#pragma unroll
        for (int q = 0; q < HIDN / 2; ++q) pin_h2(whh[g][q]);
#pragma unroll
        for (int q = 0; q < II / 2; ++q)   pin_h2(wih[g][q]);
        pin_f(bias[g]);
    }

    float cst   = 0.0f;
    int  packed = 0;                      // h(-1) pair = {0,0}

    const _Float16* xhp = xh + b * II;
    h2 xv[II / 2], xn[II / 2];
    auto ldx = [&](int t, h2* dst) {
        // 32B broadcast load; t==TT over-reads into workspace slack (safe)
        const h8* p = (const h8*)(xhp + (size_t)t * BB * II);
        union { h8 v; h2 p2[4]; } u0, u1;
        u0.v = p[0];
        u1.v = p[1];
#pragma unroll
        for (int i = 0; i < 4; ++i) { dst[i] = u0.p2[i]; dst[4 + i] = u1.p2[i]; }
    };
    ldx(0, xv);

    h4* sptr = (h4*)(stage_f16 + (size_t)c * 256 + lane * 4);

    for (int t4 = 0; t4 < T4; ++t4) {
        union { h4 v4; _Float16 e[4]; } hpk;
#pragma unroll
        for (int j = 0; j < 4; ++j) {
            const int t = t4 * 4 + j;
            ldx(t + 1, xn);               // consumed next step (vmcnt-covered)

            float z0 = bias[0], z1 = bias[1], z2 = bias[2], z3 = bias[3];
            // x-projection first (independent of h broadcast)
#pragma unroll
            for (int q = 0; q < II / 2; ++q) {
                z0 = fdot2(wih[0][q], xv[q], z0);
                z1 = fdot2(wih[1][q], xv[q], z1);
                z2 = fdot2(wih[2][q], xv[q], z2);
                z3 = fdot2(wih[3][q], xv[q], z3);
            }
            // h-projection: wave-uniform h2 pairs via readlane -> SGPR
#pragma unroll
            for (int q = 0; q < HIDN / 2; ++q) {
                h2 hq = __builtin_bit_cast(h2,
                            __builtin_amdgcn_readlane(packed, 2 * q));
                z0 = fdot2(whh[0][q], hq, z0);
                z1 = fdot2(whh[1][q], hq, z1);
                z2 = fdot2(whh[2][q], hq, z2);
                z3 = fdot2(whh[3][q], hq, z3);
            }

            float gi = fast_sigmoid(z0);
            float gf = fast_sigmoid(z1);
            float gg = fast_tanh(z2);
            float go = fast_sigmoid(z3);

            cst = fmaf(gf, cst, gi * gg);
            float hv = go * fast_tanh(cst);
            _Float16 h16 = (_Float16)hv;   // RNE, same numerics as LDS version
            hpk.e[j] = h16;

            // pack {h[2*floor(L/2)], h[2*floor(L/2)+1]} for next step
            int h32 = (int)__builtin_bit_cast(unsigned short, h16);
            int hsw = __builtin_amdgcn_mov_dpp(h32, 0xB1, 0xF, 0xF, true); // lane^1
            int lo  = odd ? hsw : h32;
            int hi  = odd ? h32 : hsw;
            packed  = lo | (hi << 16);

#pragma unroll
            for (int q = 0; q < II / 2; ++q) xv[q] = xn[q];
        }
        *sptr = hpk.v4;                   // 8B fire-and-forget, acks amortized x4
        sptr += 512 * 64;
    }
}

// ---------------- legacy one-wave-per-chain kernel (fallback modes) ----------------
template <int STAGE, bool XF16>
__global__ __launch_bounds__(64, 1)
void lstm_wave(const float* __restrict__ x,
               const _Float16* __restrict__ xh,
               const float* __restrict__ Wih,
               const float* __restrict__ Whh,
               const float* __restrict__ bih,
               const float* __restrict__ bhh,
               const float* __restrict__ Wlin,
               const float* __restrict__ blin,
               float* __restrict__ out,
               float* __restrict__ lstm_out,
               _Float16* __restrict__ stage_f16)
{
    const int lane = threadIdx.x;
    const int c    = blockIdx.x;
    const int b    = c & (BB - 1);
    const int hd   = c >> 6;

    h2 whh[4][HIDN / 2];
    h2 wih[4][II / 2];
    float bias[4];
#pragma unroll
    for (int g = 0; g < 4; ++g) {
        const int r = hd * GG + g * HIDN + lane;
        const float4* p = (const float4*)(Whh + (size_t)r * HIDN);
#pragma unroll
        for (int q = 0; q < HIDN / 4; ++q) {
            float4 v = p[q];
            whh[g][2 * q]     = h2{ (_Float16)v.x, (_Float16)v.y };
            whh[g][2 * q + 1] = h2{ (_Float16)v.z, (_Float16)v.w };
        }
        const float4* pi = (const float4*)(Wih + (size_t)r * II);
#pragma unroll
        for (int q = 0; q < II / 4; ++q) {
            float4 v = pi[q];
            wih[g][2 * q]     = h2{ (_Float16)v.x, (_Float16)v.y };
            wih[g][2 * q + 1] = h2{ (_Float16)v.z, (_Float16)v.w };
        }
        bias[g] = bih[r] + bhh[r];
    }
    float wl = 0.0f, blv = 0.0f;
    if (STAGE == 2) { wl = Wlin[hd * HIDN + lane]; blv = blin[hd]; }

    __shared__ __align__(16) _Float16 hbuf[HIDN];
    hbuf[lane] = (_Float16)0.0f;

    float cst = 0.0f;

    const _Float16* xhp = xh + b * II;
    const float*    xfp = x + b * II;
    h2 xv[II / 2];
    auto load_x = [&](int t, h2* dst) {
        int tc = t < TT ? t : TT - 1;
        if (XF16) {
            const h8* p = (const h8*)(xhp + (size_t)tc * BB * II);
            union { h8 v; h2 p2[4]; } u0, u1;
            u0.v = p[0];
            u1.v = p[1];
#pragma unroll
            for (int i = 0; i < 4; ++i) { dst[i] = u0.p2[i]; dst[4 + i] = u1.p2[i]; }
        } else {
            const float4* p = (const float4*)(xfp + (size_t)tc * BB * II);
#pragma unroll
            for (int q = 0; q < 4; ++q) {
                float4 v = p[q];
                dst[2 * q]     = h2{ (_Float16)v.x, (_Float16)v.y };
                dst[2 * q + 1] = h2{ (_Float16)v.z, (_Float16)v.w };
            }
        }
    };
    load_x(0, xv);

    h4* sptr = (h4*)(stage_f16 + (size_t)c * 256 + lane * 4);

    for (int t4 = 0; t4 < T4; ++t4) {
        union { h4 v4; h2 p2[2]; } hp;
#pragma unroll
        for (int j = 0; j < 4; ++j) {
            const int t = t4 * 4 + j;
            h2 xn[II / 2];
            load_x(t + 1, xn);

            union { h8 v[8]; h2 p[32]; } hr;
#pragma unroll
            for (int q = 0; q < 8; ++q) hr.v[q] = ((const h8*)hbuf)[q];

            float z0 = bias[0], z1 = bias[1], z2 = bias[2], z3 = bias[3];
#pragma unroll
            for (int q = 0; q < HIDN / 2; ++q) {
                z0 = fdot2(whh[0][q], hr.p[q], z0);
                z1 = fdot2(whh[1][q], hr.p[q], z1);
                z2 = fdot2(whh[2][q], hr.p[q], z2);
                z3 = fdot2(whh[3][q], hr.p[q], z3);
            }
#pragma unroll
            for (int q = 0; q < II / 2; ++q) {
                z0 = fdot2(wih[0][q], xv[q], z0);
                z1 = fdot2(wih[1][q], xv[q], z1);
                z2 = fdot2(wih[2][q], xv[q], z2);
                z3 = fdot2(wih[3][q], xv[q], z3);
            }

            float gi = fast_sigmoid(z0);
            float gf = fast_sigmoid(z1);
            float gg = fast_tanh(z2);
            float go = fast_sigmoid(z3);

            cst = fmaf(gf, cst, gi * gg);
            float h = go * fast_tanh(cst);
            _Float16 h16 = (_Float16)h;

            hbuf[lane] = h16;
            hp.p2[j >> 1][j & 1] = h16;

            if (STAGE == 2) {
                atomicAdd(&lstm_out[((size_t)t * BB + b) * HIDN + lane], h);
                float p = h * wl;
                p += __shfl_down(p, 32, 64);
                p += __shfl_down(p, 16, 64);
                p += __shfl_down(p, 8, 64);
                p += __shfl_down(p, 4, 64);
                p += __shfl_down(p, 2, 64);
                p += __shfl_down(p, 1, 64);
                if (lane == 0) out[((size_t)t * BB + b) * HH + hd] = p + blv;
            }

#pragma unroll
            for (int q = 0; q < II / 2; ++q) xv[q] = xn[q];
        }
        if (STAGE == 1) {
            *sptr = hp.v4;
            sptr += 512 * 64;
        }
    }
}

// ---------------- pass 2a: lstm_out[t,b,k] = sum_hd h ----------------
__global__ __launch_bounds__(256)
void pass_lstm(const _Float16* __restrict__ stage, float* __restrict__ lstm_out)
{
    const int tid  = threadIdx.x;
    const int k    = tid & (HIDN - 1);
    const int q    = tid >> 6;
    const int b    = blockIdx.x & (BB - 1);
    const int tile = blockIdx.x >> 6;
    const h4* sp = (const h4*)stage;

#pragma unroll
    for (int g = 0; g < 4; ++g) {
        const int t4 = tile * 16 + q + 4 * g;
        float acc0 = 0.f, acc1 = 0.f, acc2 = 0.f, acc3 = 0.f;
#pragma unroll
        for (int hd = 0; hd < HH; ++hd) {
            h4 v = sp[((size_t)t4 * 512 + hd * 64 + b) * 64 + k];
            acc0 += (float)v.x; acc1 += (float)v.y;
            acc2 += (float)v.z; acc3 += (float)v.w;
        }
        const size_t t = (size_t)t4 * 4;
        lstm_out[((t + 0) * BB + b) * HIDN + k] = acc0;
        lstm_out[((t + 1) * BB + b) * HIDN + k] = acc1;
        lstm_out[((t + 2) * BB + b) * HIDN + k] = acc2;
        lstm_out[((t + 3) * BB + b) * HIDN + k] = acc3;
    }
}

// ---------------- pass 2b: out[t,b,hd] = dot(h, W_lin)+b_lin ----------------
__global__ __launch_bounds__(512)
void pass_out(const _Float16* __restrict__ stage,
              const float* __restrict__ Wlin,
              const float* __restrict__ blin,
              float* __restrict__ out)
{
    __shared__ float wls[GG * 2];
    const int tid = threadIdx.x;
    wls[tid] = Wlin[tid];
    __syncthreads();

    const int b  = tid >> 3;
    const int hd = tid & 7;
    const int c  = hd * 64 + b;
    const int t4 = blockIdx.x;
    const float bl = blin[hd];

    const h4* sp = (const h4*)stage + ((size_t)t4 * 512 + c) * 64;
    float a0 = 0.f, a1 = 0.f, a2 = 0.f, a3 = 0.f;
#pragma unroll 8
    for (int k = 0; k < HIDN; ++k) {
        h4 v = sp[k];
        float w = wls[hd * HIDN + k];
        a0 = fmaf((float)v.x, w, a0);
        a1 = fmaf((float)v.y, w, a1);
        a2 = fmaf((float)v.z, w, a2);
        a3 = fmaf((float)v.w, w, a3);
    }
    const size_t t = (size_t)t4 * 4;
    out[(t + 0) * 512 + tid] = a0 + bl;
    out[(t + 1) * 512 + tid] = a1 + bl;
    out[(t + 2) * 512 + tid] = a2 + bl;
    out[(t + 3) * 512 + tid] = a3 + bl;
}

extern "C" void kernel_launch(void* const* d_in, const int* in_sizes, int n_in,
                              void* d_out, int out_size, void* d_ws, size_t ws_size,
                              hipStream_t stream)
{
    const float* x    = (const float*)d_in[0];
    const float* Wih  = (const float*)d_in[1];
    const float* Whh  = (const float*)d_in[2];
    const float* bih  = (const float*)d_in[3];
    const float* bhh  = (const float*)d_in[4];
    const float* Wlin = (const float*)d_in[5];
    const float* blin = (const float*)d_in[6];

    float* out  = (float*)d_out;
    float* lstm = out + (size_t)TT * BB * HH;

    const size_t xbytes = (size_t)TT * BB * II * 2 + 4096;   // 4 MB + prefetch slack
    const size_t slab16 = (size_t)TT * BB * HH * HIDN * 2;   // 134 MB

    const bool xf16 = ws_size >= xbytes;
    _Float16* xh = (_Float16*)d_ws;
    char* slabp  = (char*)d_ws + (xf16 ? xbytes : 0);
    size_t avail = ws_size - (xf16 ? xbytes : 0);
    const int mode = (avail >= slab16) ? 1 : 2;

    if (xf16) {
        int n4 = TT * BB * II / 4;
        cvt_x_kernel<<<(n4 + 255) / 256, 256, 0, stream>>>(x, xh, n4);
    }

    _Float16* sh = (_Float16*)slabp;

    if (mode == 1 && xf16) {
        // SGPR-broadcast recurrent kernel: 512 blocks x 64 threads, zero LDS
        lstm_rl<<<dim3(BB * HH), dim3(64), 0, stream>>>(xh, Wih, Whh, bih, bhh, sh);
        pass_lstm<<<dim3(BB * 32), dim3(256), 0, stream>>>(sh, lstm);
        pass_out <<<dim3(T4), dim3(512), 0, stream>>>(sh, Wlin, blin, out);
    } else if (mode == 1) {
        dim3 grid(BB * HH), block(64);
        lstm_wave<1, false><<<grid, block, 0, stream>>>(x, xh, Wih, Whh, bih, bhh,
                                                        Wlin, blin, out, lstm, sh);
        pass_lstm<<<dim3(BB * 32), dim3(256), 0, stream>>>(sh, lstm);
        pass_out <<<dim3(T4), dim3(512), 0, stream>>>(sh, Wlin, blin, out);
    } else {
        hipMemsetAsync(lstm, 0, (size_t)TT * BB * HIDN * 4, stream);
        dim3 grid(BB * HH), block(64);
        if (xf16)
            lstm_wave<2, true><<<grid, block, 0, stream>>>(x, xh, Wih, Whh, bih, bhh,
                                                           Wlin, blin, out, lstm, sh);
        else
            lstm_wave<2, false><<<grid, block, 0, stream>>>(x, xh, Wih, Whh, bih, bhh,
                                                            Wlin, blin, out, lstm, sh);
    }
}

// Round 7
// 1085.983 us; speedup vs baseline: 1.0801x; 1.0801x over previous
//
#include <hip/hip_runtime.h>
#include <hip/hip_fp16.h>

#define TT   2048
#define BB   64
#define II   16
#define HH   8
#define HIDN 64
#define GG   256   // 4*HIDN
#define T4   (TT / 4)

typedef _Float16 h2 __attribute__((ext_vector_type(2)));
typedef _Float16 h4 __attribute__((ext_vector_type(4)));
typedef _Float16 h8 __attribute__((ext_vector_type(8)));

__device__ __forceinline__ float fdot2(h2 a, h2 b, float c) {
    return __builtin_amdgcn_fdot2(a, b, c, false);
}
__device__ __forceinline__ float fast_sigmoid(float z) {
    return __builtin_amdgcn_rcpf(1.0f + __expf(-z));
}
__device__ __forceinline__ float fast_tanh(float z) {
    return fmaf(2.0f, __builtin_amdgcn_rcpf(1.0f + __expf(-2.0f * z)), -1.0f);
}

// ---------------- x -> f16 conversion (one-time, trivial) ----------------
__global__ void cvt_x_kernel(const float* __restrict__ x, _Float16* __restrict__ xh, int n4) {
    int i = blockIdx.x * blockDim.x + threadIdx.x;
    if (i < n4) {
        float4 v = ((const float4*)x)[i];
        ((h2*)xh)[2 * i]     = h2{ (_Float16)v.x, (_Float16)v.y };
        ((h2*)xh)[2 * i + 1] = h2{ (_Float16)v.z, (_Float16)v.w };
    }
}

// 64 KB LDS footprint: hbuf (used) + pad (dead). Referencing the struct
// variable keeps the WHOLE allocation -> hardware occupancy is capped at
// 2 workgroups/CU = 1 wave/EU. This forces the register allocator's budget
// to ~256 arch VGPRs through the occupancy formula itself (launch_bounds /
// amdgpu_waves_per_eu failed to do this: VGPR_Count stayed 124 = the
// 4-wave/EU budget, and the ~164 VGPRs of weight state were remat/reloaded
// from L2 every step -- 5.2 GB/launch, which at ~4.3 TB/s per-XCD L2 BW is
// ~1.2 ms: the floor every variant hit). With the budget raised, keeping
// the weights resident is free and the L2 weight stream disappears.
struct SmemPad {
    _Float16 hbuf[HIDN];
    char     pad[63872];   // total 64000 B: 2 blocks/CU (<=160KB), never 3
};

// ------------- main recurrent kernel: register-resident weights -----------
// One wave per chain (512 blocks x 64 threads). h exchange via wave-local
// LDS broadcast (in-order pipe, no barriers) -- the R0 champion structure.
// Micro-opts vs R0:
//  * 8-way accumulator split (zA/zB per gate): the 40-deep fdot2 chains had
//    only 4-way ILP (8-cyc reissue vs ~6-cyc dep latency -> bubbles).
//  * software-pipelined x-projection: xz(t+1) = bias + W_ih.x(t+1) is
//    computed in the gate/LDS-roundtrip shadow of step t; step t's z starts
//    from the ready xz registers, so the critical path is h-dots only.
__global__ __launch_bounds__(64, 1)
void lstm_reg(const _Float16* __restrict__ xh,
              const float* __restrict__ Wih,
              const float* __restrict__ Whh,
              const float* __restrict__ bih,
              const float* __restrict__ bhh,
              _Float16* __restrict__ stage_f16)   // [t4][chain][unit][4] h4
{
    const int lane = threadIdx.x;          // hidden unit index
    const int c    = blockIdx.x;           // chain id
    const int b    = c & (BB - 1);
    const int hd   = c >> 6;

    __shared__ __align__(16) SmemPad smem;

    // ---- per-lane weights: the 4 gate rows of this unit, f16 in VGPRs ----
    h2 whh[4][HIDN / 2];
    h2 wih[4][II / 2];
    float bias[4];
#pragma unroll
    for (int g = 0; g < 4; ++g) {
        const int r = hd * GG + g * HIDN + lane;  // PyTorch gate-major row
        const float4* p = (const float4*)(Whh + (size_t)r * HIDN);
#pragma unroll
        for (int q = 0; q < HIDN / 4; ++q) {
            float4 v = p[q];
            whh[g][2 * q]     = h2{ (_Float16)v.x, (_Float16)v.y };
            whh[g][2 * q + 1] = h2{ (_Float16)v.z, (_Float16)v.w };
        }
        const float4* pi = (const float4*)(Wih + (size_t)r * II);
#pragma unroll
        for (int q = 0; q < II / 4; ++q) {
            float4 v = pi[q];
            wih[g][2 * q]     = h2{ (_Float16)v.x, (_Float16)v.y };
            wih[g][2 * q + 1] = h2{ (_Float16)v.z, (_Float16)v.w };
        }
        bias[g] = bih[r] + bhh[r];
    }

    smem.hbuf[lane] = (_Float16)0.0f;      // h(-1) = 0 (in-order LDS pipe)
    if (lane == 0) smem.pad[0] = 1;        // keep the pad allocation live

    float cst = 0.0f;

    const _Float16* xhp = xh + b * II;
    h2 xn[II / 2];
    auto ldx = [&](int t, h2* dst) {
        // 32B broadcast load; t==TT over-reads into workspace slack (safe)
        const h8* p = (const h8*)(xhp + (size_t)t * BB * II);
        union { h8 v; h2 p2[4]; } u0, u1;
        u0.v = p[0];
        u1.v = p[1];
#pragma unroll
        for (int i = 0; i < 4; ++i) { dst[i] = u0.p2[i]; dst[4 + i] = u1.p2[i]; }
    };

    // prime the xz pipeline for t=0
    float xzA[4], xzB[4];
    ldx(0, xn);
#pragma unroll
    for (int g = 0; g < 4; ++g) { xzA[g] = bias[g]; xzB[g] = 0.0f; }
#pragma unroll
    for (int q = 0; q < 4; ++q)
#pragma unroll
        for (int g = 0; g < 4; ++g) xzA[g] = fdot2(wih[g][q], xn[q], xzA[g]);
#pragma unroll
    for (int q = 4; q < 8; ++q)
#pragma unroll
        for (int g = 0; g < 4; ++g) xzB[g] = fdot2(wih[g][q], xn[q], xzB[g]);

    h4* sptr = (h4*)(stage_f16 + (size_t)c * 256 + lane * 4);

    for (int t4 = 0; t4 < T4; ++t4) {
        union { h4 v4; _Float16 e[4]; } hpk;
#pragma unroll
        for (int j = 0; j < 4; ++j) {
            const int t = t4 * 4 + j;

            // broadcast-read h(t-1): 8 x ds_read_b128, conflict-free
            union { h8 v[8]; h2 p[32]; } hr;
#pragma unroll
            for (int q = 0; q < 8; ++q) hr.v[q] = ((const h8*)smem.hbuf)[q];

            ldx(t + 1, xn);               // consumed at this step's tail

            // h-dots: 8 independent accumulator chains (4 gates x 2 halves)
            float zA0 = xzA[0], zA1 = xzA[1], zA2 = xzA[2], zA3 = xzA[3];
            float zB0 = xzB[0], zB1 = xzB[1], zB2 = xzB[2], zB3 = xzB[3];
#pragma unroll
            for (int q = 0; q < 16; ++q) {
                zA0 = fdot2(whh[0][q], hr.p[q], zA0);
                zA1 = fdot2(whh[1][q], hr.p[q], zA1);
                zA2 = fdot2(whh[2][q], hr.p[q], zA2);
                zA3 = fdot2(whh[3][q], hr.p[q], zA3);
            }
#pragma unroll
            for (int q = 16; q < 32; ++q) {
                zB0 = fdot2(whh[0][q], hr.p[q], zB0);
                zB1 = fdot2(whh[1][q], hr.p[q], zB1);
                zB2 = fdot2(whh[2][q], hr.p[q], zB2);
                zB3 = fdot2(whh[3][q], hr.p[q], zB3);
            }
            float z0 = zA0 + zB0, z1 = zA1 + zB1;
            float z2 = zA2 + zB2, z3 = zA3 + zB3;

            float gi = fast_sigmoid(z0);
            float gf = fast_sigmoid(z1);
            float gg = fast_tanh(z2);
            float go = fast_sigmoid(z3);

            cst = fmaf(gf, cst, gi * gg);
            float hv = go * fast_tanh(cst);
            _Float16 h16 = (_Float16)hv;

            smem.hbuf[lane] = h16;        // in-order after this step's reads
            hpk.e[j] = h16;

            // x-projection for step t+1, in the gate/LDS-roundtrip shadow
#pragma unroll
            for (int g = 0; g < 4; ++g) { xzA[g] = bias[g]; xzB[g] = 0.0f; }
#pragma unroll
            for (int q = 0; q < 4; ++q)
#pragma unroll
                for (int g = 0; g < 4; ++g)
                    xzA[g] = fdot2(wih[g][q], xn[q], xzA[g]);
#pragma unroll
            for (int q = 4; q < 8; ++q)
#pragma unroll
                for (int g = 0; g < 4; ++g)
                    xzB[g] = fdot2(wih[g][q], xn[q], xzB[g]);
        }
        *sptr = hpk.v4;                   // 8B fire-and-forget, acks amortized x4
        sptr += 512 * 64;
    }
}

// ---------------- legacy one-wave-per-chain kernel (fallback modes) ----------------
template <int STAGE, bool XF16>
__global__ __launch_bounds__(64, 1)
void lstm_wave(const float* __restrict__ x,
               const _Float16* __restrict__ xh,
               const float* __restrict__ Wih,
               const float* __restrict__ Whh,
               const float* __restrict__ bih,
               const float* __restrict__ bhh,
               const float* __restrict__ Wlin,
               const float* __restrict__ blin,
               float* __restrict__ out,
               float* __restrict__ lstm_out,
               _Float16* __restrict__ stage_f16)
{
    const int lane = threadIdx.x;
    const int c    = blockIdx.x;
    const int b    = c & (BB - 1);
    const int hd   = c >> 6;

    h2 whh[4][HIDN / 2];
    h2 wih[4][II / 2];
    float bias[4];
#pragma unroll
    for (int g = 0; g < 4; ++g) {
        const int r = hd * GG + g * HIDN + lane;
        const float4* p = (const float4*)(Whh + (size_t)r * HIDN);
#pragma unroll
        for (int q = 0; q < HIDN / 4; ++q) {
            float4 v = p[q];
            whh[g][2 * q]     = h2{ (_Float16)v.x, (_Float16)v.y };
            whh[g][2 * q + 1] = h2{ (_Float16)v.z, (_Float16)v.w };
        }
        const float4* pi = (const float4*)(Wih + (size_t)r * II);
#pragma unroll
        for (int q = 0; q < II / 4; ++q) {
            float4 v = pi[q];
            wih[g][2 * q]     = h2{ (_Float16)v.x, (_Float16)v.y };
            wih[g][2 * q + 1] = h2{ (_Float16)v.z, (_Float16)v.w };
        }
        bias[g] = bih[r] + bhh[r];
    }
    float wl = 0.0f, blv = 0.0f;
    if (STAGE == 2) { wl = Wlin[hd * HIDN + lane]; blv = blin[hd]; }

    __shared__ __align__(16) _Float16 hbuf[HIDN];
    hbuf[lane] = (_Float16)0.0f;

    float cst = 0.0f;

    const _Float16* xhp = xh + b * II;
    const float*    xfp = x + b * II;
    h2 xv[II / 2];
    auto load_x = [&](int t, h2* dst) {
        int tc = t < TT ? t : TT - 1;
        if (XF16) {
            const h8* p = (const h8*)(xhp + (size_t)tc * BB * II);
            union { h8 v; h2 p2[4]; } u0, u1;
            u0.v = p[0];
            u1.v = p[1];
#pragma unroll
            for (int i = 0; i < 4; ++i) { dst[i] = u0.p2[i]; dst[4 + i] = u1.p2[i]; }
        } else {
            const float4* p = (const float4*)(xfp + (size_t)tc * BB * II);
#pragma unroll
            for (int q = 0; q < 4; ++q) {
                float4 v = p[q];
                dst[2 * q]     = h2{ (_Float16)v.x, (_Float16)v.y };
                dst[2 * q + 1] = h2{ (_Float16)v.z, (_Float16)v.w };
            }
        }
    };
    load_x(0, xv);

    h4* sptr = (h4*)(stage_f16 + (size_t)c * 256 + lane * 4);

    for (int t4 = 0; t4 < T4; ++t4) {
        union { h4 v4; h2 p2[2]; } hp;
#pragma unroll
        for (int j = 0; j < 4; ++j) {
            const int t = t4 * 4 + j;
            h2 xn[II / 2];
            load_x(t + 1, xn);

            union { h8 v[8]; h2 p[32]; } hr;
#pragma unroll
            for (int q = 0; q < 8; ++q) hr.v[q] = ((const h8*)hbuf)[q];

            float z0 = bias[0], z1 = bias[1], z2 = bias[2], z3 = bias[3];
#pragma unroll
            for (int q = 0; q < HIDN / 2; ++q) {
                z0 = fdot2(whh[0][q], hr.p[q], z0);
                z1 = fdot2(whh[1][q], hr.p[q], z1);
                z2 = fdot2(whh[2][q], hr.p[q], z2);
                z3 = fdot2(whh[3][q], hr.p[q], z3);
            }
#pragma unroll
            for (int q = 0; q < II / 2; ++q) {
                z0 = fdot2(wih[0][q], xv[q], z0);
                z1 = fdot2(wih[1][q], xv[q], z1);
                z2 = fdot2(wih[2][q], xv[q], z2);
                z3 = fdot2(wih[3][q], xv[q], z3);
            }

            float gi = fast_sigmoid(z0);
            float gf = fast_sigmoid(z1);
            float gg = fast_tanh(z2);
            float go = fast_sigmoid(z3);

            cst = fmaf(gf, cst, gi * gg);
            float h = go * fast_tanh(cst);
            _Float16 h16 = (_Float16)h;

            hbuf[lane] = h16;
            hp.p2[j >> 1][j & 1] = h16;

            if (STAGE == 2) {
                atomicAdd(&lstm_out[((size_t)t * BB + b) * HIDN + lane], h);
                float p = h * wl;
                p += __shfl_down(p, 32, 64);
                p += __shfl_down(p, 16, 64);
                p += __shfl_down(p, 8, 64);
                p += __shfl_down(p, 4, 64);
                p += __shfl_down(p, 2, 64);
                p += __shfl_down(p, 1, 64);
                if (lane == 0) out[((size_t)t * BB + b) * HH + hd] = p + blv;
            }

#pragma unroll
            for (int q = 0; q < II / 2; ++q) xv[q] = xn[q];
        }
        if (STAGE == 1) {
            *sptr = hp.v4;
            sptr += 512 * 64;
        }
    }
}

// ---------------- pass 2a: lstm_out[t,b,k] = sum_hd h ----------------
__global__ __launch_bounds__(256)
void pass_lstm(const _Float16* __restrict__ stage, float* __restrict__ lstm_out)
{
    const int tid  = threadIdx.x;
    const int k    = tid & (HIDN - 1);
    const int q    = tid >> 6;
    const int b    = blockIdx.x & (BB - 1);
    const int tile = blockIdx.x >> 6;
    const h4* sp = (const h4*)stage;

#pragma unroll
    for (int g = 0; g < 4; ++g) {
        const int t4 = tile * 16 + q + 4 * g;
        float acc0 = 0.f, acc1 = 0.f, acc2 = 0.f, acc3 = 0.f;
#pragma unroll
        for (int hd = 0; hd < HH; ++hd) {
            h4 v = sp[((size_t)t4 * 512 + hd * 64 + b) * 64 + k];
            acc0 += (float)v.x; acc1 += (float)v.y;
            acc2 += (float)v.z; acc3 += (float)v.w;
        }
        const size_t t = (size_t)t4 * 4;
        lstm_out[((t + 0) * BB + b) * HIDN + k] = acc0;
        lstm_out[((t + 1) * BB + b) * HIDN + k] = acc1;
        lstm_out[((t + 2) * BB + b) * HIDN + k] = acc2;
        lstm_out[((t + 3) * BB + b) * HIDN + k] = acc3;
    }
}

// ---------------- pass 2b: out[t,b,hd] = dot(h, W_lin)+b_lin ----------------
__global__ __launch_bounds__(512)
void pass_out(const _Float16* __restrict__ stage,
              const float* __restrict__ Wlin,
              const float* __restrict__ blin,
              float* __restrict__ out)
{
    __shared__ float wls[GG * 2];
    const int tid = threadIdx.x;
    wls[tid] = Wlin[tid];
    __syncthreads();

    const int b  = tid >> 3;
    const int hd = tid & 7;
    const int c  = hd * 64 + b;
    const int t4 = blockIdx.x;
    const float bl = blin[hd];

    const h4* sp = (const h4*)stage + ((size_t)t4 * 512 + c) * 64;
    float a0 = 0.f, a1 = 0.f, a2 = 0.f, a3 = 0.f;
#pragma unroll 8
    for (int k = 0; k < HIDN; ++k) {
        h4 v = sp[k];
        float w = wls[hd * HIDN + k];
        a0 = fmaf((float)v.x, w, a0);
        a1 = fmaf((float)v.y, w, a1);
        a2 = fmaf((float)v.z, w, a2);
        a3 = fmaf((float)v.w, w, a3);
    }
    const size_t t = (size_t)t4 * 4;
    out[(t + 0) * 512 + tid] = a0 + bl;
    out[(t + 1) * 512 + tid] = a1 + bl;
    out[(t + 2) * 512 + tid] = a2 + bl;
    out[(t + 3) * 512 + tid] = a3 + bl;
}

extern "C" void kernel_launch(void* const* d_in, const int* in_sizes, int n_in,
                              void* d_out, int out_size, void* d_ws, size_t ws_size,
                              hipStream_t stream)
{
    const float* x    = (const float*)d_in[0];
    const float* Wih  = (const float*)d_in[1];
    const float* Whh  = (const float*)d_in[2];
    const float* bih  = (const float*)d_in[3];
    const float* bhh  = (const float*)d_in[4];
    const float* Wlin = (const float*)d_in[5];
    const float* blin = (const float*)d_in[6];

    float* out  = (float*)d_out;
    float* lstm = out + (size_t)TT * BB * HH;

    const size_t xbytes = (size_t)TT * BB * II * 2 + 4096;   // 4 MB + prefetch slack
    const size_t slab16 = (size_t)TT * BB * HH * HIDN * 2;   // 134 MB

    const bool xf16 = ws_size >= xbytes;
    _Float16* xh = (_Float16*)d_ws;
    char* slabp  = (char*)d_ws + (xf16 ? xbytes : 0);
    size_t avail = ws_size - (xf16 ? xbytes : 0);
    const int mode = (avail >= slab16) ? 1 : 2;

    if (xf16) {
        int n4 = TT * BB * II / 4;
        cvt_x_kernel<<<(n4 + 255) / 256, 256, 0, stream>>>(x, xh, n4);
    }

    _Float16* sh = (_Float16*)slabp;

    if (mode == 1 && xf16) {
        // register-resident-weight kernel: 512 blocks x 64 threads, 64KB LDS
        lstm_reg<<<dim3(BB * HH), dim3(64), 0, stream>>>(xh, Wih, Whh, bih, bhh, sh);
        pass_lstm<<<dim3(BB * 32), dim3(256), 0, stream>>>(sh, lstm);
        pass_out <<<dim3(T4), dim3(512), 0, stream>>>(sh, Wlin, blin, out);
    } else if (mode == 1) {
        dim3 grid(BB * HH), block(64);
        lstm_wave<1, false><<<grid, block, 0, stream>>>(x, xh, Wih, Whh, bih, bhh,
                                                        Wlin, blin, out, lstm, sh);
        pass_lstm<<<dim3(BB * 32), dim3(256), 0, stream>>>(sh, lstm);
        pass_out <<<dim3(T4), dim3(512), 0, stream>>>(sh, Wlin, blin, out);
    } else {
        hipMemsetAsync(lstm, 0, (size_t)TT * BB * HIDN * 4, stream);
        dim3 grid(BB * HH), block(64);
        if (xf16)
            lstm_wave<2, true><<<grid, block, 0, stream>>>(x, xh, Wih, Whh, bih, bhh,
                                                           Wlin, blin, out, lstm, sh);
        else
            lstm_wave<2, false><<<grid, block, 0, stream>>>(x, xh, Wih, Whh, bih, bhh,
                                                            Wlin, blin, out, lstm, sh);
    }
}